// Round 1
// baseline (590.190 us; speedup 1.0000x reference)
//
#include <hip/hip_runtime.h>
#include <hip/hip_bf16.h>

// Problem constants
#define TN 2000
#define UN 50000
#define TF 16
#define NCOL 48      // padded N: 36 emb cols + ones col (36) + 11 zero cols
#define UNP 50016    // padded K: covers last MFMA k-group (49984+32), multiple of 8
#define KSTEPS 1563  // ceil(50000/32)
#define KCHUNKS 48
#define SPC 33       // ceil(1563/48)
#define MTILES 125   // 2000/16

typedef __attribute__((ext_vector_type(8))) short short8;
typedef __attribute__((ext_vector_type(4))) float f32x4;

__device__ inline unsigned short f2bf(float f) {
    unsigned int x = __float_as_uint(f);
    x += 0x7FFFu + ((x >> 16) & 1u);      // round-to-nearest-even
    return (unsigned short)(x >> 16);
}

// Kernel 1: gather per-user embeddings into bf16, N-major padded layout UT[n][k]
__global__ void build_uembT(const int* __restrict__ U,
                            const float* __restrict__ e0, const float* __restrict__ e1,
                            const float* __restrict__ e2, const float* __restrict__ e3,
                            const float* __restrict__ e4, const float* __restrict__ e5,
                            unsigned short* __restrict__ UT) {
    int u = blockIdx.x * 256 + threadIdx.x;
    if (u >= UNP) return;
    const float* tabs[6] = {e0, e1, e2, e3, e4, e5};
    if (u < UN) {
        #pragma unroll
        for (int f = 0; f < 6; ++f) {
            int idx = U[u * 6 + f];
            #pragma unroll
            for (int h = 0; h < 6; ++h)
                UT[(size_t)(f * 6 + h) * UNP + u] = f2bf(tabs[f][idx * 6 + h]);
        }
        UT[(size_t)36 * UNP + u] = 0x3F80;   // ones column -> counts
    } else {
        #pragma unroll
        for (int c = 0; c < 37; ++c) UT[(size_t)c * UNP + u] = 0;
    }
    #pragma unroll
    for (int c = 37; c < NCOL; ++c) UT[(size_t)c * UNP + u] = 0;
}

// Kernel 2: bf16 MFMA GEMM  accum[m][n] += sum_k mask(m,k) * UT[n][k]
__global__ __launch_bounds__(256) void masked_gemm(
        const int* __restrict__ mask, const unsigned short* __restrict__ UT,
        float* __restrict__ accum) {
    int wave = threadIdx.x >> 6;
    int lane = threadIdx.x & 63;
    int mtile = blockIdx.x * 4 + wave;
    if (mtile >= MTILES) return;          // wave-uniform early-exit
    int m0 = mtile * 16;
    int r  = lane & 15;
    int g8 = (lane >> 4) * 8;

    int ks0 = blockIdx.y * SPC;
    int ks1 = ks0 + SPC; if (ks1 > KSTEPS) ks1 = KSTEPS;

    f32x4 acc0 = {0.f, 0.f, 0.f, 0.f};
    f32x4 acc1 = {0.f, 0.f, 0.f, 0.f};
    f32x4 acc2 = {0.f, 0.f, 0.f, 0.f};

    const int* arow = mask + (size_t)(m0 + r) * UN;           // A row (team m0+r)
    const unsigned short* b0 = UT + (size_t)(r)      * UNP;   // B rows (n)
    const unsigned short* b1 = UT + (size_t)(r + 16) * UNP;
    const unsigned short* b2 = UT + (size_t)(r + 32) * UNP;

    for (int ks = ks0; ks < ks1; ++ks) {
        int gk = ks * 32 + g8;            // this lane-group's k start (mult of 8)
        short8 a;
        if (gk < UN) {                    // whole 8-group valid (50000 % 8 == 0)
            const int4* p = (const int4*)(arow + gk);
            int4 v0 = p[0], v1 = p[1];
            int v[8] = {v0.x, v0.y, v0.z, v0.w, v1.x, v1.y, v1.z, v1.w};
            #pragma unroll
            for (int j = 0; j < 8; ++j) a[j] = (v[j] == 1) ? (short)0x3F80 : (short)0;
        } else {
            #pragma unroll
            for (int j = 0; j < 8; ++j) a[j] = (short)0;
        }
        short8 f0 = *(const short8*)(b0 + gk);
        short8 f1 = *(const short8*)(b1 + gk);
        short8 f2 = *(const short8*)(b2 + gk);
        acc0 = __builtin_amdgcn_mfma_f32_16x16x32_bf16(a, f0, acc0, 0, 0, 0);
        acc1 = __builtin_amdgcn_mfma_f32_16x16x32_bf16(a, f1, acc1, 0, 0, 0);
        acc2 = __builtin_amdgcn_mfma_f32_16x16x32_bf16(a, f2, acc2, 0, 0, 0);
    }

    // C/D layout: col = lane&15, row = (lane>>4)*4 + reg   [HW-verified]
    int row0 = m0 + (lane >> 4) * 4;
    int col  = lane & 15;
    #pragma unroll
    for (int reg = 0; reg < 4; ++reg)
        atomicAdd(&accum[(size_t)(row0 + reg) * NCOL + col], acc0[reg]);
    #pragma unroll
    for (int reg = 0; reg < 4; ++reg)
        atomicAdd(&accum[(size_t)(row0 + reg) * NCOL + col + 16], acc1[reg]);
    if (col < 5) {   // only cols 32..36 are live in tile 2
        #pragma unroll
        for (int reg = 0; reg < 4; ++reg)
            atomicAdd(&accum[(size_t)(row0 + reg) * NCOL + col + 32], acc2[reg]);
    }
}

// Kernel 3: out[t] = concat(T_static[t], accum[t][0:36] / accum[t][36])
__global__ void finalize(const float* __restrict__ T_static,
                         const float* __restrict__ accum,
                         float* __restrict__ out) {
    int t = blockIdx.x;
    int c = threadIdx.x;
    if (c >= TF + 36) return;
    float v;
    if (c < TF) {
        v = T_static[(size_t)t * TF + c];
    } else {
        float cnt = accum[(size_t)t * NCOL + 36];
        v = accum[(size_t)t * NCOL + (c - TF)] / cnt;
    }
    out[(size_t)t * (TF + 36) + c] = v;
}

extern "C" void kernel_launch(void* const* d_in, const int* in_sizes, int n_in,
                              void* d_out, int out_size, void* d_ws, size_t ws_size,
                              hipStream_t stream) {
    const float* T_static = (const float*)d_in[0];
    const int*   U_static = (const int*)d_in[1];
    const int*   mask     = (const int*)d_in[2];
    const float* e0 = (const float*)d_in[3];
    const float* e1 = (const float*)d_in[4];
    const float* e2 = (const float*)d_in[5];
    const float* e3 = (const float*)d_in[6];
    const float* e4 = (const float*)d_in[7];
    const float* e5 = (const float*)d_in[8];
    float* out = (float*)d_out;

    unsigned short* UT = (unsigned short*)d_ws;
    size_t ut_bytes = (size_t)NCOL * UNP * sizeof(unsigned short);  // 4,801,536 B
    float* accum = (float*)((char*)d_ws + ut_bytes);                // 2000*48*4 B

    hipMemsetAsync(accum, 0, (size_t)TN * NCOL * sizeof(float), stream);
    build_uembT<<<dim3((UNP + 255) / 256), dim3(256), 0, stream>>>(
        U_static, e0, e1, e2, e3, e4, e5, UT);
    masked_gemm<<<dim3(32, KCHUNKS), dim3(256), 0, stream>>>(mask, UT, accum);
    finalize<<<dim3(TN), dim3(64), 0, stream>>>(T_static, accum, out);
}

// Round 2
// 587.459 us; speedup vs baseline: 1.0046x; 1.0046x over previous
//
#include <hip/hip_runtime.h>
#include <hip/hip_bf16.h>

// Problem constants
#define TN 2000
#define UN 50000
#define TF 16
#define NCOL 48      // padded N: 36 emb cols + ones col (36) + 11 zero cols
#define UNP 50016    // padded K: covers last MFMA k-group, multiple of 32
#define KSTEPS 1563  // ceil(50000/32); step 1562 is the partial tail
#define KFULL 1562   // steps with all 32 k valid (50000 = 1562*32 + 16)
#define KCHUNKS 48
#define SPC 33       // ceil(1563/48)
#define MTILES 125   // 2000/16

typedef __attribute__((ext_vector_type(8))) short short8;
typedef __attribute__((ext_vector_type(4))) float f32x4;

__device__ inline unsigned short f2bf(float f) {
    unsigned int x = __float_as_uint(f);
    x += 0x7FFFu + ((x >> 16) & 1u);      // round-to-nearest-even
    return (unsigned short)(x >> 16);
}

// Kernel 1: gather per-user embeddings into bf16, N-major padded layout UT[c][u]
// grid: (ceil(UNP/256), NCOL) — one thread per (user, column)
__global__ void build_uembT(const int* __restrict__ U,
                            const float* __restrict__ e0, const float* __restrict__ e1,
                            const float* __restrict__ e2, const float* __restrict__ e3,
                            const float* __restrict__ e4, const float* __restrict__ e5,
                            unsigned short* __restrict__ UT) {
    int u = blockIdx.x * 256 + threadIdx.x;
    int c = blockIdx.y;                    // 0..47, wave-uniform
    if (u >= UNP) return;
    unsigned short val = 0;
    if (u < UN) {
        if (c < 36) {
            int f = c / 6, h = c - f * 6;  // uniform scalar math
            const float* t = (f == 0) ? e0 : (f == 1) ? e1 : (f == 2) ? e2
                           : (f == 3) ? e3 : (f == 4) ? e4 : e5;
            int idx = U[u * 6 + f];
            val = f2bf(t[idx * 6 + h]);
        } else if (c == 36) {
            val = 0x3F80;                  // ones column -> counts
        }
    }
    UT[(size_t)c * UNP + u] = val;
}

__device__ inline short8 mask_to_bf16(const int v[8]) {
    union { short8 s; int i[4]; } a;
    #pragma unroll
    for (int j = 0; j < 4; ++j) {
        int lo = (v[2 * j]     == 1) ? 0x3F80     : 0;
        int hi = (v[2 * j + 1] == 1) ? 0x3F800000 : 0;   // 1.0f bits = inline const
        a.i[j] = lo | hi;
    }
    return a.s;
}

// Kernel 2: bf16 MFMA GEMM  partial[ky][m][n] = sum_{k in chunk ky} mask(m,k)*UT[n][k]
__global__ __launch_bounds__(256) void masked_gemm(
        const int* __restrict__ mask, const unsigned short* __restrict__ UT,
        float* __restrict__ partial) {
    int wave = threadIdx.x >> 6;
    int lane = threadIdx.x & 63;
    int mtile = blockIdx.x * 4 + wave;
    if (mtile >= MTILES) return;          // wave-uniform early-exit
    int m0 = mtile * 16;
    int r  = lane & 15;
    int g8 = (lane >> 4) * 8;
    int ky = blockIdx.y;

    int ks0 = ky * SPC;
    int ks1 = ks0 + SPC; if (ks1 > KSTEPS) ks1 = KSTEPS;
    int ksf = (ks1 < KFULL) ? ks1 : KFULL;   // full (unguarded) steps

    f32x4 acc0 = {0.f, 0.f, 0.f, 0.f};
    f32x4 acc1 = {0.f, 0.f, 0.f, 0.f};
    f32x4 acc2 = {0.f, 0.f, 0.f, 0.f};

    const int* arow = mask + (size_t)(m0 + r) * UN + g8;      // A row (team m0+r)
    const unsigned short* b0 = UT + (size_t)(r)      * UNP + g8;
    const unsigned short* b1 = UT + (size_t)(r + 16) * UNP + g8;
    const unsigned short* b2 = UT + (size_t)(r + 32) * UNP + g8;

    #pragma unroll 3
    for (int ks = ks0; ks < ksf; ++ks) {
        int gk = ks * 32;
        const int4* p = (const int4*)(arow + gk);
        int4 v0 = p[0], v1 = p[1];
        int v[8] = {v0.x, v0.y, v0.z, v0.w, v1.x, v1.y, v1.z, v1.w};
        short8 a  = mask_to_bf16(v);
        short8 f0 = *(const short8*)(b0 + gk);
        short8 f1 = *(const short8*)(b1 + gk);
        short8 f2 = *(const short8*)(b2 + gk);
        acc0 = __builtin_amdgcn_mfma_f32_16x16x32_bf16(a, f0, acc0, 0, 0, 0);
        acc1 = __builtin_amdgcn_mfma_f32_16x16x32_bf16(a, f1, acc1, 0, 0, 0);
        acc2 = __builtin_amdgcn_mfma_f32_16x16x32_bf16(a, f2, acc2, 0, 0, 0);
    }
    if (ks1 > KFULL) {                    // tail step (only chunk 47): k 49984..50015
        int gk = KFULL * 32;
        short8 a = {0,0,0,0,0,0,0,0};
        if (g8 < 16) {                    // k-groups at 49984, 49992 are fully valid
            const int4* p = (const int4*)(arow + gk);
            int4 v0 = p[0], v1 = p[1];
            int v[8] = {v0.x, v0.y, v0.z, v0.w, v1.x, v1.y, v1.z, v1.w};
            a = mask_to_bf16(v);
        }
        short8 f0 = *(const short8*)(b0 + gk);
        short8 f1 = *(const short8*)(b1 + gk);
        short8 f2 = *(const short8*)(b2 + gk);
        acc0 = __builtin_amdgcn_mfma_f32_16x16x32_bf16(a, f0, acc0, 0, 0, 0);
        acc1 = __builtin_amdgcn_mfma_f32_16x16x32_bf16(a, f1, acc1, 0, 0, 0);
        acc2 = __builtin_amdgcn_mfma_f32_16x16x32_bf16(a, f2, acc2, 0, 0, 0);
    }

    // C/D layout: col = lane&15, row = (lane>>4)*4 + reg   [HW-verified]
    int row0 = m0 + (lane >> 4) * 4;
    int col  = lane & 15;
    float* out = partial + ((size_t)ky * TN) * NCOL;
    #pragma unroll
    for (int reg = 0; reg < 4; ++reg) {
        size_t rb = (size_t)(row0 + reg) * NCOL;
        out[rb + col]      = acc0[reg];
        out[rb + col + 16] = acc1[reg];
        out[rb + col + 32] = acc2[reg];
    }
}

// Kernel 3: out[t] = concat(T_static[t], sum_ky partial[ky][t][0:36] / sum_ky partial[ky][t][36])
__global__ void finalize(const float* __restrict__ T_static,
                         const float* __restrict__ partial,
                         float* __restrict__ out) {
    int t = blockIdx.x;
    int c = threadIdx.x;
    if (c >= TF + 36) return;
    float v;
    if (c < TF) {
        v = T_static[(size_t)t * TF + c];
    } else {
        int n = c - TF;
        float s = 0.f, cnt = 0.f;
        #pragma unroll 4
        for (int ky = 0; ky < KCHUNKS; ++ky) {
            const float* row = partial + ((size_t)ky * TN + t) * NCOL;
            s   += row[n];
            cnt += row[36];
        }
        v = s / cnt;
    }
    out[(size_t)t * (TF + 36) + c] = v;
}

extern "C" void kernel_launch(void* const* d_in, const int* in_sizes, int n_in,
                              void* d_out, int out_size, void* d_ws, size_t ws_size,
                              hipStream_t stream) {
    const float* T_static = (const float*)d_in[0];
    const int*   U_static = (const int*)d_in[1];
    const int*   mask     = (const int*)d_in[2];
    const float* e0 = (const float*)d_in[3];
    const float* e1 = (const float*)d_in[4];
    const float* e2 = (const float*)d_in[5];
    const float* e3 = (const float*)d_in[6];
    const float* e4 = (const float*)d_in[7];
    const float* e5 = (const float*)d_in[8];
    float* out = (float*)d_out;

    unsigned short* UT = (unsigned short*)d_ws;
    size_t ut_bytes = (size_t)NCOL * UNP * sizeof(unsigned short);  // 4,801,536 B
    float* partial = (float*)((char*)d_ws + ut_bytes);  // 48*2000*48*4 = 18.4 MB

    build_uembT<<<dim3((UNP + 255) / 256, NCOL), dim3(256), 0, stream>>>(
        U_static, e0, e1, e2, e3, e4, e5, UT);
    masked_gemm<<<dim3(32, KCHUNKS), dim3(256), 0, stream>>>(mask, UT, partial);
    finalize<<<dim3(TN), dim3(64), 0, stream>>>(T_static, partial, out);
}